// Round 1
// baseline (1598.907 us; speedup 1.0000x reference)
//
#include <hip/hip_runtime.h>
#include <hip/hip_bf16.h>

// LightGCN: 3-layer weighted propagation + user-item score GEMM.
// Strategy: build dst-sorted CSR per call (hist + scan + scatter-permute),
// then gather-style layers (no float atomics), then fp32 tiled GEMM.
// acc/rep ping-pong buffers live in d_out (overwritten by final GEMM).

#define N_NODES   100000
#define N_EDGES   3200000
#define EMBED     128
#define N_USERS_T 50000   // n_users from reference setup
#define N_ITEMS   50000   // N_NODES - n_users

// ---------------- histogram ----------------
__global__ __launch_bounds__(256) void hist_kernel(const int* __restrict__ dst,
                                                   int* __restrict__ counts, int n) {
    int i = blockIdx.x * 256 + threadIdx.x;
    if (i < n) atomicAdd(&counts[dst[i]], 1);
}

// ---------------- single-block exclusive scan over counts ----------------
__global__ __launch_bounds__(1024) void scan_kernel(const int* __restrict__ counts,
                                                    int* __restrict__ offsets, int n) {
    __shared__ int wsum[16];
    __shared__ int carry_s;
    if (threadIdx.x == 0) carry_s = 0;
    __syncthreads();
    for (int base = 0; base < n; base += 1024) {
        int i = base + (int)threadIdx.x;
        int v = (i < n) ? counts[i] : 0;
        int lane = threadIdx.x & 63;
        int wid  = threadIdx.x >> 6;
        int x = v;
        #pragma unroll
        for (int off = 1; off < 64; off <<= 1) {
            int y = __shfl_up(x, off, 64);
            if (lane >= off) x += y;
        }
        if (lane == 63) wsum[wid] = x;
        __syncthreads();
        int c = carry_s;
        int wprefix = 0;
        for (int j = 0; j < wid; ++j) wprefix += wsum[j];
        if (i < n) offsets[i] = c + wprefix + x - v;   // exclusive
        __syncthreads();
        if (threadIdx.x == 0) {
            int tot = 0;
            for (int j = 0; j < 16; ++j) tot += wsum[j];
            carry_s += tot;
        }
        __syncthreads();
    }
}

// ---------------- scatter-permute edges by dst ----------------
// atomicAdd on offsets turns it into inclusive-end array (end of bucket d).
__global__ __launch_bounds__(256) void scatter_kernel(const int* __restrict__ src,
                                                      const int* __restrict__ dst,
                                                      const float* __restrict__ w,
                                                      int* __restrict__ off,
                                                      int* __restrict__ ss,
                                                      float* __restrict__ sw, int n) {
    int i = blockIdx.x * 256 + threadIdx.x;
    if (i < n) {
        int d = dst[i];
        int p = atomicAdd(&off[d], 1);
        ss[p] = src[i];
        sw[p] = w[i];
    }
}

// ---------------- one propagation layer: gather per node ----------------
// one wave per node, 64 lanes x float2 = 128 features; also acc += rep_new
__global__ __launch_bounds__(256) void layer_kernel(const float* __restrict__ rep_in,
                                                    float* __restrict__ rep_out,
                                                    float* __restrict__ acc,
                                                    const int* __restrict__ off_end,
                                                    const int* __restrict__ ss,
                                                    const float* __restrict__ sw,
                                                    int n_nodes) {
    int node = blockIdx.x * 4 + (threadIdx.x >> 6);
    if (node >= n_nodes) return;
    int lane = threadIdx.x & 63;
    int beg = (node == 0) ? 0 : off_end[node - 1];
    int end = off_end[node];
    float sx = 0.f, sy = 0.f;
    const float2* rp = (const float2*)rep_in;
    for (int e = beg; e < end; ++e) {
        int   sn = ss[e];
        float wt = sw[e];
        float2 r = rp[(size_t)sn * 64 + lane];
        sx = fmaf(wt, r.x, sx);
        sy = fmaf(wt, r.y, sy);
    }
    float2* ro = (float2*)rep_out;
    float2 sv; sv.x = sx; sv.y = sy;
    ro[(size_t)node * 64 + lane] = sv;
    float2* ac = (float2*)acc;
    float2 a = ac[(size_t)node * 64 + lane];
    a.x += sx; a.y += sy;
    ac[(size_t)node * 64 + lane] = a;
}

// ---------------- gather user rows (x0.25) ----------------
__global__ __launch_bounds__(256) void gather_users(const int* __restrict__ users,
                                                    const float* __restrict__ acc,
                                                    float* __restrict__ ur, int nu) {
    int idx = blockIdx.x * 256 + threadIdx.x;     // nu*32 threads
    int u = idx >> 5;
    int k = (idx & 31) * 4;
    if (u < nu) {
        const float4 v = *(const float4*)(acc + (size_t)users[u] * EMBED + k);
        float4 o; o.x = v.x * 0.25f; o.y = v.y * 0.25f; o.z = v.z * 0.25f; o.w = v.w * 0.25f;
        *(float4*)(ur + (size_t)u * EMBED + k) = o;
    }
}

// ---------------- copy item rows (x0.25) ----------------
__global__ __launch_bounds__(256) void copy_items(const float* __restrict__ acc,
                                                  float* __restrict__ ir, int ni) {
    int idx = blockIdx.x * 256 + threadIdx.x;     // ni*32 threads
    int i = idx >> 5;
    int k = (idx & 31) * 4;
    if (i < ni) {
        const float4 v = *(const float4*)(acc + (size_t)(N_USERS_T + i) * EMBED + k);
        float4 o; o.x = v.x * 0.25f; o.y = v.y * 0.25f; o.z = v.z * 0.25f; o.w = v.w * 0.25f;
        *(float4*)(ir + (size_t)i * EMBED + k) = o;
    }
}

// ---------------- fp32 GEMM: C[1024 x nI] = U[1024 x 128] * I[nI x 128]^T --------
__global__ __launch_bounds__(256) void gemm_kernel(const float* __restrict__ U,
                                                   const float* __restrict__ I,
                                                   float* __restrict__ C, int nI) {
    __shared__ float Us[64][64];   // [k][row]
    __shared__ float Is[64][64];
    const int t  = threadIdx.x;
    const int u0 = blockIdx.y * 64;
    const int i0 = blockIdx.x * 64;
    const int tx = t & 15, ty = t >> 4;
    float acc[4][4] = {};
    for (int k0 = 0; k0 < EMBED; k0 += 64) {
        __syncthreads();
        #pragma unroll
        for (int it = 0; it < 4; ++it) {
            int idx = it * 256 + t;        // 0..1023
            int row = idx & 63;
            int k4  = (idx >> 6) * 4;      // 0..60
            float4 uv = *(const float4*)(U + (size_t)(u0 + row) * EMBED + k0 + k4);
            int irow = i0 + row;
            float4 iv; iv.x = iv.y = iv.z = iv.w = 0.f;
            if (irow < nI) iv = *(const float4*)(I + (size_t)irow * EMBED + k0 + k4);
            Us[k4 + 0][row] = uv.x; Us[k4 + 1][row] = uv.y;
            Us[k4 + 2][row] = uv.z; Us[k4 + 3][row] = uv.w;
            Is[k4 + 0][row] = iv.x; Is[k4 + 1][row] = iv.y;
            Is[k4 + 2][row] = iv.z; Is[k4 + 3][row] = iv.w;
        }
        __syncthreads();
        #pragma unroll
        for (int k = 0; k < 64; ++k) {
            float4 a = *(const float4*)(&Us[k][ty * 4]);
            float4 b = *(const float4*)(&Is[k][tx * 4]);
            acc[0][0] = fmaf(a.x, b.x, acc[0][0]);
            acc[0][1] = fmaf(a.x, b.y, acc[0][1]);
            acc[0][2] = fmaf(a.x, b.z, acc[0][2]);
            acc[0][3] = fmaf(a.x, b.w, acc[0][3]);
            acc[1][0] = fmaf(a.y, b.x, acc[1][0]);
            acc[1][1] = fmaf(a.y, b.y, acc[1][1]);
            acc[1][2] = fmaf(a.y, b.z, acc[1][2]);
            acc[1][3] = fmaf(a.y, b.w, acc[1][3]);
            acc[2][0] = fmaf(a.z, b.x, acc[2][0]);
            acc[2][1] = fmaf(a.z, b.y, acc[2][1]);
            acc[2][2] = fmaf(a.z, b.z, acc[2][2]);
            acc[2][3] = fmaf(a.z, b.w, acc[2][3]);
            acc[3][0] = fmaf(a.w, b.x, acc[3][0]);
            acc[3][1] = fmaf(a.w, b.y, acc[3][1]);
            acc[3][2] = fmaf(a.w, b.z, acc[3][2]);
            acc[3][3] = fmaf(a.w, b.w, acc[3][3]);
        }
    }
    // store
    if (i0 + 64 <= nI) {
        #pragma unroll
        for (int r = 0; r < 4; ++r) {
            float4 o; o.x = acc[r][0]; o.y = acc[r][1]; o.z = acc[r][2]; o.w = acc[r][3];
            *(float4*)(C + (size_t)(u0 + ty * 4 + r) * nI + i0 + tx * 4) = o;
        }
    } else {
        #pragma unroll
        for (int r = 0; r < 4; ++r)
            #pragma unroll
            for (int c = 0; c < 4; ++c) {
                int ii = i0 + tx * 4 + c;
                if (ii < nI) C[(size_t)(u0 + ty * 4 + r) * nI + ii] = acc[r][c];
            }
    }
}

extern "C" void kernel_launch(void* const* d_in, const int* in_sizes, int n_in,
                              void* d_out, int out_size, void* d_ws, size_t ws_size,
                              hipStream_t stream) {
    const float* emb   = (const float*)d_in[0];
    const float* ew    = (const float*)d_in[1];
    const int*   esrc  = (const int*)d_in[2];
    const int*   edst  = (const int*)d_in[3];
    const int*   users = (const int*)d_in[4];
    const int n_edges = in_sizes[1];
    const int n_nodes = in_sizes[0] / EMBED;
    const int nu      = in_sizes[4];

    // ---- workspace layout (~52.5 MB) ----
    char* ws = (char*)d_ws;
    int*   counts  = (int*)ws;                                  // 400000 B
    int*   offsets = (int*)(ws + 400128);                       // 400000 B
    int*   ss      = (int*)(ws + 800256);                       // 12.8 MB
    float* sw      = (float*)(ws + 800256 + 12800000);          // 12.8 MB
    float* ur      = (float*)(ws + 800256 + 25600000);          // 512 KB
    float* ir      = (float*)(ws + 800256 + 25600000 + 524288); // 25.6 MB

    // ---- acc / rep ping-pong live in d_out (fully overwritten by GEMM) ----
    float* out   = (float*)d_out;
    float* acc   = out;                          // 12.8M floats
    float* rep_a = out + (size_t)N_NODES * EMBED;        // 12.8M floats
    float* rep_b = out + (size_t)2 * N_NODES * EMBED;    // 12.8M floats

    // 1) CSR build
    hipMemsetAsync(counts, 0, (size_t)n_nodes * sizeof(int), stream);
    hist_kernel<<<(n_edges + 255) / 256, 256, 0, stream>>>(edst, counts, n_edges);
    scan_kernel<<<1, 1024, 0, stream>>>(counts, offsets, n_nodes);
    scatter_kernel<<<(n_edges + 255) / 256, 256, 0, stream>>>(esrc, edst, ew,
                                                              offsets, ss, sw, n_edges);

    // 2) acc = embedding
    hipMemcpyAsync(acc, emb, (size_t)N_NODES * EMBED * sizeof(float),
                   hipMemcpyDeviceToDevice, stream);

    // 3) three propagation layers (gather), fused acc +=
    const int lgrid = (n_nodes + 3) / 4;
    layer_kernel<<<lgrid, 256, 0, stream>>>(emb,   rep_a, acc, offsets, ss, sw, n_nodes);
    layer_kernel<<<lgrid, 256, 0, stream>>>(rep_a, rep_b, acc, offsets, ss, sw, n_nodes);
    layer_kernel<<<lgrid, 256, 0, stream>>>(rep_b, rep_a, acc, offsets, ss, sw, n_nodes);

    // 4) gather user rows and item rows (x0.25 each -> product x1/16)
    gather_users<<<(nu * 32 + 255) / 256, 256, 0, stream>>>(users, acc, ur, nu);
    copy_items<<<(N_ITEMS * 32 + 255) / 256, 256, 0, stream>>>(acc, ir, N_ITEMS);

    // 5) scores = ur @ ir^T
    dim3 ggrid((N_ITEMS + 63) / 64, nu / 64);
    gemm_kernel<<<ggrid, 256, 0, stream>>>(ur, ir, out, N_ITEMS);
}

// Round 2
// 1279.059 us; speedup vs baseline: 1.2501x; 1.2501x over previous
//
#include <hip/hip_runtime.h>
#include <hip/hip_bf16.h>

typedef float f4 __attribute__((ext_vector_type(4)));

#define N_NODES   100000
#define EMBED     128
#define N_USERS_T 50000
#define N_ITEMS   50000

// ---------------- histogram ----------------
__global__ __launch_bounds__(256) void hist_kernel(const int* __restrict__ dst,
                                                   int* __restrict__ counts, int n) {
    int i = blockIdx.x * 256 + threadIdx.x;
    if (i < n) atomicAdd(&counts[dst[i]], 1);
}

// ---------------- single-block exclusive scan over counts ----------------
__global__ __launch_bounds__(1024) void scan_kernel(const int* __restrict__ counts,
                                                    int* __restrict__ offsets, int n) {
    __shared__ int wsum[16];
    __shared__ int carry_s;
    if (threadIdx.x == 0) carry_s = 0;
    __syncthreads();
    for (int base = 0; base < n; base += 1024) {
        int i = base + (int)threadIdx.x;
        int v = (i < n) ? counts[i] : 0;
        int lane = threadIdx.x & 63;
        int wid  = threadIdx.x >> 6;
        int x = v;
        #pragma unroll
        for (int off = 1; off < 64; off <<= 1) {
            int y = __shfl_up(x, off, 64);
            if (lane >= off) x += y;
        }
        if (lane == 63) wsum[wid] = x;
        __syncthreads();
        int c = carry_s;
        int wprefix = 0;
        for (int j = 0; j < wid; ++j) wprefix += wsum[j];
        if (i < n) offsets[i] = c + wprefix + x - v;   // exclusive
        __syncthreads();
        if (threadIdx.x == 0) {
            int tot = 0;
            for (int j = 0; j < 16; ++j) tot += wsum[j];
            carry_s += tot;
        }
        __syncthreads();
    }
}

// ---------------- scatter-permute edges by dst (interleaved {src, w}) ------
__global__ __launch_bounds__(256) void scatter_kernel(const int* __restrict__ src,
                                                      const int* __restrict__ dst,
                                                      const float* __restrict__ w,
                                                      int* __restrict__ off,
                                                      int2* __restrict__ ep, int n) {
    int i = blockIdx.x * 256 + threadIdx.x;
    if (i < n) {
        int d = dst[i];
        int p = atomicAdd(&off[d], 1);
        int2 e; e.x = src[i]; e.y = __float_as_int(w[i]);
        ep[p] = e;
    }
}

// ---------------- one propagation layer: gather per node -------------------
// One wave per node. Half-waves process alternating edges; each lane holds a
// float4 (32 lanes cover the 128-feature row). Edge meta is batch-loaded 64
// at a time and broadcast via shfl -> no dependent uniform-load chain.
// Unroll 4 => 8 gathers in flight per wave.
__global__ __launch_bounds__(256) void layer_kernel(
        const float* __restrict__ rep_in, float* __restrict__ rep_out,
        const float* __restrict__ acc_in, float* __restrict__ acc_out,
        const int* __restrict__ off_end, const int2* __restrict__ ep,
        int n_nodes) {
    int node = blockIdx.x * 4 + (threadIdx.x >> 6);
    if (node >= n_nodes) return;
    int lane = threadIdx.x & 63;
    int half = lane >> 5;
    int l32  = lane & 31;
    int beg = (node == 0) ? 0 : off_end[node - 1];
    int end = off_end[node];
    f4 s = {0.f, 0.f, 0.f, 0.f};
    const f4* rp = (const f4*)rep_in;
    for (int chunk = beg; chunk < end; chunk += 64) {
        int idx = chunk + lane;
        int sn_l = 0, wb_l = 0;
        if (idx < end) { int2 e = ep[idx]; sn_l = e.x; wb_l = e.y; }
        int m = end - chunk; if (m > 64) m = 64;
        #pragma unroll 4
        for (int j = 0; j < m; j += 2) {
            int jj = j + half;                 // OOB jj==m holds {0, 0.0f}: harmless
            int   sn = __shfl(sn_l, jj);
            float wt = __int_as_float(__shfl(wb_l, jj));
            f4 r = rp[(size_t)sn * 32 + l32];
            s.x = fmaf(wt, r.x, s.x);
            s.y = fmaf(wt, r.y, s.y);
            s.z = fmaf(wt, r.z, s.z);
            s.w = fmaf(wt, r.w, s.w);
        }
    }
    // combine half-waves
    s.x += __shfl_xor(s.x, 32);
    s.y += __shfl_xor(s.y, 32);
    s.z += __shfl_xor(s.z, 32);
    s.w += __shfl_xor(s.w, 32);
    size_t p = (size_t)node * 32 + l32;
    if (half == 0) {
        __builtin_nontemporal_store(s, (f4*)rep_out + p);
    } else {
        const f4* ai = (const f4*)acc_in;
        f4 a = ai[p];
        a.x += s.x; a.y += s.y; a.z += s.z; a.w += s.w;
        __builtin_nontemporal_store(a, (f4*)acc_out + p);
    }
}

// ---------------- gather user rows (x0.25) ----------------
__global__ __launch_bounds__(256) void gather_users(const int* __restrict__ users,
                                                    const float* __restrict__ acc,
                                                    float* __restrict__ ur, int nu) {
    int idx = blockIdx.x * 256 + threadIdx.x;
    int u = idx >> 5;
    int k = (idx & 31) * 4;
    if (u < nu) {
        f4 v = *(const f4*)(acc + (size_t)users[u] * EMBED + k);
        v.x *= 0.25f; v.y *= 0.25f; v.z *= 0.25f; v.w *= 0.25f;
        *(f4*)(ur + (size_t)u * EMBED + k) = v;
    }
}

// ---------------- copy item rows (x0.25) ----------------
__global__ __launch_bounds__(256) void copy_items(const float* __restrict__ acc,
                                                  float* __restrict__ ir, int ni) {
    int idx = blockIdx.x * 256 + threadIdx.x;
    int i = idx >> 5;
    int k = (idx & 31) * 4;
    if (i < ni) {
        f4 v = *(const f4*)(acc + (size_t)(N_USERS_T + i) * EMBED + k);
        v.x *= 0.25f; v.y *= 0.25f; v.z *= 0.25f; v.w *= 0.25f;
        *(f4*)(ir + (size_t)i * EMBED + k) = v;
    }
}

// ---------------- fp32 GEMM: C[nu x nI] = U[nu x 128] * I[nI x 128]^T ------
// 128x128 tile, 256 threads, 8x8 micro-tile as 2x2 blocks of 4x4.
// LDS [k][row] with XOR swizzle (row ^ (k&28)) to kill transpose-store
// conflicts; reads are 2-way max (free). K staged in two 64-halves.
__global__ __launch_bounds__(256) void gemm_kernel(const float* __restrict__ U,
                                                   const float* __restrict__ I,
                                                   float* __restrict__ C,
                                                   int nu, int nI) {
    __shared__ float Us[64][128];
    __shared__ float Is[64][128];
    const int t  = threadIdx.x;
    const int u0 = blockIdx.y * 128;
    const int i0 = blockIdx.x * 128;
    const int tx = t & 15, ty = t >> 4;
    float acc[8][8] = {};
    for (int ks = 0; ks < 2; ++ks) {
        if (ks) __syncthreads();
        #pragma unroll
        for (int it = 0; it < 8; ++it) {
            int f  = it * 256 + t;          // 0..2047
            int r  = f >> 4;                // row 0..127
            int k4 = (f & 15) << 2;         // 0..60
            int ug = u0 + r; if (ug >= nu) ug = nu - 1;
            f4 v = *(const f4*)(U + (size_t)ug * EMBED + ks * 64 + k4);
            int ig = i0 + r;
            f4 w = {0.f, 0.f, 0.f, 0.f};
            if (ig < nI) w = *(const f4*)(I + (size_t)ig * EMBED + ks * 64 + k4);
            int cs = r ^ (k4 & 28);
            Us[k4+0][cs] = v.x; Us[k4+1][cs] = v.y;
            Us[k4+2][cs] = v.z; Us[k4+3][cs] = v.w;
            Is[k4+0][cs] = w.x; Is[k4+1][cs] = w.y;
            Is[k4+2][cs] = w.z; Is[k4+3][cs] = w.w;
        }
        __syncthreads();
        #pragma unroll 4
        for (int k = 0; k < 64; ++k) {
            int sw = k & 28;
            f4 a0 = *(const f4*)&Us[k][(ty * 4) ^ sw];
            f4 a1 = *(const f4*)&Us[k][64 + ((ty * 4) ^ sw)];
            f4 b0 = *(const f4*)&Is[k][(tx * 4) ^ sw];
            f4 b1 = *(const f4*)&Is[k][64 + ((tx * 4) ^ sw)];
            float av[8] = {a0.x, a0.y, a0.z, a0.w, a1.x, a1.y, a1.z, a1.w};
            float bv[8] = {b0.x, b0.y, b0.z, b0.w, b1.x, b1.y, b1.z, b1.w};
            #pragma unroll
            for (int r2 = 0; r2 < 8; ++r2)
                #pragma unroll
                for (int c2 = 0; c2 < 8; ++c2)
                    acc[r2][c2] = fmaf(av[r2], bv[c2], acc[r2][c2]);
        }
    }
    bool full = (i0 + 128 <= nI);
    #pragma unroll
    for (int r2 = 0; r2 < 8; ++r2) {
        int row = u0 + (r2 >> 2) * 64 + ty * 4 + (r2 & 3);
        if (row >= nu) continue;
        float* Cr = C + (size_t)row * nI;
        #pragma unroll
        for (int mi = 0; mi < 2; ++mi) {
            int col = i0 + mi * 64 + tx * 4;
            if (full) {
                f4 o = {acc[r2][mi*4+0], acc[r2][mi*4+1],
                        acc[r2][mi*4+2], acc[r2][mi*4+3]};
                *(f4*)(Cr + col) = o;
            } else {
                #pragma unroll
                for (int c = 0; c < 4; ++c)
                    if (col + c < nI) Cr[col + c] = acc[r2][mi*4+c];
            }
        }
    }
}

extern "C" void kernel_launch(void* const* d_in, const int* in_sizes, int n_in,
                              void* d_out, int out_size, void* d_ws, size_t ws_size,
                              hipStream_t stream) {
    const float* emb   = (const float*)d_in[0];
    const float* ew    = (const float*)d_in[1];
    const int*   esrc  = (const int*)d_in[2];
    const int*   edst  = (const int*)d_in[3];
    const int*   users = (const int*)d_in[4];
    const int n_edges = in_sizes[1];
    const int n_nodes = in_sizes[0] / EMBED;
    const int nu      = in_sizes[4];

    // ---- workspace layout (~52.5 MB) ----
    char* ws = (char*)d_ws;
    int*   counts  = (int*)ws;                                  // 400 KB
    int*   offsets = (int*)(ws + 400128);                       // 400 KB
    int2*  epairs  = (int2*)(ws + 800256);                      // 25.6 MB
    float* ur      = (float*)(ws + 800256 + 25600000);          // 512 KB
    float* ir      = (float*)(ws + 800256 + 25600000 + 524288); // 25.6 MB

    // ---- acc / rep ping-pong live in d_out (fully overwritten by GEMM) ----
    float* out   = (float*)d_out;
    float* acc   = out;
    float* rep_a = out + (size_t)N_NODES * EMBED;
    float* rep_b = out + (size_t)2 * N_NODES * EMBED;

    // 1) CSR build
    hipMemsetAsync(counts, 0, (size_t)n_nodes * sizeof(int), stream);
    hist_kernel<<<(n_edges + 255) / 256, 256, 0, stream>>>(edst, counts, n_edges);
    scan_kernel<<<1, 1024, 0, stream>>>(counts, offsets, n_nodes);
    scatter_kernel<<<(n_edges + 255) / 256, 256, 0, stream>>>(esrc, edst, ew,
                                                              offsets, epairs, n_edges);

    // 2) three propagation layers (gather); layer 1 fuses acc = emb + rep
    const int lgrid = (n_nodes + 3) / 4;
    layer_kernel<<<lgrid, 256, 0, stream>>>(emb,   rep_a, emb, acc, offsets, epairs, n_nodes);
    layer_kernel<<<lgrid, 256, 0, stream>>>(rep_a, rep_b, acc, acc, offsets, epairs, n_nodes);
    layer_kernel<<<lgrid, 256, 0, stream>>>(rep_b, rep_a, acc, acc, offsets, epairs, n_nodes);

    // 3) gather user rows and item rows (x0.25 each -> product x1/16)
    gather_users<<<(nu * 32 + 255) / 256, 256, 0, stream>>>(users, acc, ur, nu);
    copy_items<<<(N_ITEMS * 32 + 255) / 256, 256, 0, stream>>>(acc, ir, N_ITEMS);

    // 4) scores = ur @ ir^T
    dim3 ggrid((N_ITEMS + 127) / 128, (nu + 127) / 128);
    gemm_kernel<<<ggrid, 256, 0, stream>>>(ur, ir, out, nu, N_ITEMS);
}

// Round 5
// 714.737 us; speedup vs baseline: 2.2371x; 1.7896x over previous
//
#include <hip/hip_runtime.h>
#include <hip/hip_bf16.h>
#include <hip/hip_fp16.h>

typedef float f4 __attribute__((ext_vector_type(4)));
typedef unsigned int u32x2 __attribute__((ext_vector_type(2)));

__device__ __forceinline__ __half2 bits2h2(unsigned u) {
    union { unsigned u; __half2 h; } c; c.u = u; return c.h;
}
__device__ __forceinline__ unsigned h22bits(__half2 h) {
    union { unsigned u; __half2 h; } c; c.h = h; return c.u;
}

#define N_NODES   100000
#define EMBED     128
#define N_USERS_T 50000
#define N_ITEMS   50000

#define BSH   8                 // bucket = dst >> 8
#define NB    391               // ceil(100000 / 256)
#define NBLK  256               // partition blocks

// ---------- K1: per-block bucket histogram ----------
__global__ __launch_bounds__(256) void part_hist(const int* __restrict__ dst,
                                                 int* __restrict__ blkhist,
                                                 int n, int epb) {
    __shared__ int h[NB];
    for (int j = threadIdx.x; j < NB; j += 256) h[j] = 0;
    __syncthreads();
    int b = blockIdx.x, s = b * epb, e = min(n, s + epb);
    for (int i = s + (int)threadIdx.x; i < e; i += 256)
        atomicAdd(&h[dst[i] >> BSH], 1);
    __syncthreads();
    for (int j = threadIdx.x; j < NB; j += 256) blkhist[b * NB + j] = h[j];
}

// ---------- K2a: per-bucket exclusive scan across blocks ----------
__global__ __launch_bounds__(256) void part_cursors(const int* __restrict__ blkhist,
                                                    int* __restrict__ cursors,
                                                    int* __restrict__ total) {
    int bu = blockIdx.x, t = threadIdx.x;
    int v = blkhist[t * NB + bu];
    int lane = t & 63, wid = t >> 6;
    int x = v;
    #pragma unroll
    for (int off = 1; off < 64; off <<= 1) {
        int y = __shfl_up(x, off, 64);
        if (lane >= off) x += y;
    }
    __shared__ int ws4[4];
    if (lane == 63) ws4[wid] = x;
    __syncthreads();
    int add = 0;
    for (int j = 0; j < wid; ++j) add += ws4[j];
    cursors[t * NB + bu] = add + x - v;      // exclusive over blocks
    if (t == 255) total[bu] = add + x;       // bucket size
}

// ---------- K2b: bucket base (serial tiny scan) ----------
__global__ void bucket_base_scan(const int* __restrict__ total,
                                 int* __restrict__ base) {
    if (threadIdx.x == 0) {
        int s = 0;
        for (int j = 0; j < NB; ++j) { base[j] = s; s += total[j]; }
        base[NB] = s;
    }
}

// ---------- K3: partition into buckets (block-private slices) ----------
// part entry: .x = src | (dst_low8 << 17), .y = w bits
__global__ __launch_bounds__(256) void part_scatter(const int* __restrict__ src,
                                                    const int* __restrict__ dst,
                                                    const float* __restrict__ w,
                                                    const int* __restrict__ cursors,
                                                    const int* __restrict__ base,
                                                    int2* __restrict__ part,
                                                    int n, int epb) {
    __shared__ int cur[NB];
    int b = blockIdx.x;
    for (int j = threadIdx.x; j < NB; j += 256)
        cur[j] = base[j] + cursors[b * NB + j];
    __syncthreads();
    int s = b * epb, e = min(n, s + epb);
    for (int i = s + (int)threadIdx.x; i < e; i += 256) {
        int d = dst[i];
        int bu = d >> BSH;
        int p = atomicAdd(&cur[bu], 1);
        int2 pe;
        pe.x = src[i] | ((d & 255) << 17);
        pe.y = __float_as_int(w[i]);
        part[p] = pe;
    }
}

// ---------- K4: per-bucket fine CSR (count, scan, scatter; L2-local) ------
__global__ __launch_bounds__(512) void bucket_csr(const int2* __restrict__ part,
                                                  const int* __restrict__ base,
                                                  int* __restrict__ off_end,
                                                  int2* __restrict__ ep,
                                                  int n_nodes) {
    __shared__ int cnt[256], cur2[256], ws4[4];
    int bu = blockIdx.x, t = threadIdx.x;
    int b0 = base[bu], b1 = base[bu + 1];
    if (t < 256) cnt[t] = 0;
    __syncthreads();
    for (int i = b0 + t; i < b1; i += 512)
        atomicAdd(&cnt[(part[i].x >> 17) & 255], 1);
    __syncthreads();
    int lane = t & 63, wid = t >> 6;
    int v = 0, x = 0;
    if (t < 256) {
        v = cnt[t]; x = v;
        #pragma unroll
        for (int off = 1; off < 64; off <<= 1) {
            int y = __shfl_up(x, off, 64);
            if (lane >= off) x += y;
        }
        if (lane == 63) ws4[wid] = x;
    }
    __syncthreads();
    if (t < 256) {
        int add = 0;
        for (int j = 0; j < wid; ++j) add += ws4[j];
        int incl = add + x;
        int node = (bu << BSH) + t;
        if (node < n_nodes) off_end[node] = b0 + incl;
        cur2[t] = b0 + incl - v;             // exclusive start
    }
    __syncthreads();
    for (int i = b0 + t; i < b1; i += 512) {
        int2 pe = part[i];
        int dloc = (pe.x >> 17) & 255;
        int p = atomicAdd(&cur2[dloc], 1);
        int2 o; o.x = pe.x & 0x1FFFF; o.y = pe.y;
        ep[p] = o;
    }
}

// ---------- fp32 -> fp16 row conversion ----------
__global__ __launch_bounds__(256) void f2h_kernel(const float* __restrict__ in,
                                                  __half* __restrict__ out, int n4) {
    int i = blockIdx.x * 256 + threadIdx.x;
    if (i < n4) {
        f4 v = ((const f4*)in)[i];
        u32x2 o;
        o.x = h22bits(__floats2half2_rn(v.x, v.y));
        o.y = h22bits(__floats2half2_rn(v.z, v.w));
        ((u32x2*)out)[i] = o;
    }
}

// ---------- propagation layer: fp16 gather, fp32 accumulate ----------
__global__ __launch_bounds__(256) void layer_kernel(
        const __half* __restrict__ rep_in, __half* __restrict__ rep_out,
        const float* __restrict__ acc_in, float* __restrict__ acc_out,
        const int* __restrict__ off_end, const int2* __restrict__ ep,
        int n_nodes) {
    int node = blockIdx.x * 4 + (threadIdx.x >> 6);
    if (node >= n_nodes) return;
    int lane = threadIdx.x & 63;
    int half = lane >> 5;
    int l32  = lane & 31;
    int beg = (node == 0) ? 0 : off_end[node - 1];
    int end = off_end[node];
    f4 s = {0.f, 0.f, 0.f, 0.f};
    const u32x2* rp = (const u32x2*)rep_in;
    for (int chunk = beg; chunk < end; chunk += 64) {
        int idx = chunk + lane;
        int sn_l = 0, wb_l = 0;
        if (idx < end) { int2 e = ep[idx]; sn_l = e.x; wb_l = e.y; }
        int m = end - chunk; if (m > 64) m = 64;
        #pragma unroll 4
        for (int j = 0; j < m; j += 2) {
            int jj = j + half;                 // jj==m edge holds {0,0}: harmless
            int   sn = __shfl(sn_l, jj);
            float wt = __int_as_float(__shfl(wb_l, jj));
            u32x2 rv = rp[(size_t)sn * 32 + l32];
            float2 f0 = __half22float2(bits2h2(rv.x));
            float2 f1 = __half22float2(bits2h2(rv.y));
            s.x = fmaf(wt, f0.x, s.x);
            s.y = fmaf(wt, f0.y, s.y);
            s.z = fmaf(wt, f1.x, s.z);
            s.w = fmaf(wt, f1.y, s.w);
        }
    }
    s.x += __shfl_xor(s.x, 32);
    s.y += __shfl_xor(s.y, 32);
    s.z += __shfl_xor(s.z, 32);
    s.w += __shfl_xor(s.w, 32);
    size_t p = (size_t)node * 32 + l32;
    if (half == 0) {
        u32x2 ov;
        ov.x = h22bits(__floats2half2_rn(s.x, s.y));
        ov.y = h22bits(__floats2half2_rn(s.z, s.w));
        __builtin_nontemporal_store(ov, (u32x2*)rep_out + p);
    } else {
        f4 a = ((const f4*)acc_in)[p];
        a.x += s.x; a.y += s.y; a.z += s.z; a.w += s.w;
        __builtin_nontemporal_store(a, (f4*)acc_out + p);
    }
}

// ---------- gather user rows (x0.25) ----------
__global__ __launch_bounds__(256) void gather_users(const int* __restrict__ users,
                                                    const float* __restrict__ acc,
                                                    float* __restrict__ ur, int nu) {
    int idx = blockIdx.x * 256 + threadIdx.x;
    int u = idx >> 5;
    int k = (idx & 31) * 4;
    if (u < nu) {
        f4 v = *(const f4*)(acc + (size_t)users[u] * EMBED + k);
        v.x *= 0.25f; v.y *= 0.25f; v.z *= 0.25f; v.w *= 0.25f;
        *(f4*)(ur + (size_t)u * EMBED + k) = v;
    }
}

// ---------- copy item rows (x0.25) ----------
__global__ __launch_bounds__(256) void copy_items(const float* __restrict__ acc,
                                                  float* __restrict__ ir, int ni) {
    int idx = blockIdx.x * 256 + threadIdx.x;
    int i = idx >> 5;
    int k = (idx & 31) * 4;
    if (i < ni) {
        f4 v = *(const f4*)(acc + (size_t)(N_USERS_T + i) * EMBED + k);
        v.x *= 0.25f; v.y *= 0.25f; v.z *= 0.25f; v.w *= 0.25f;
        *(f4*)(ir + (size_t)i * EMBED + k) = v;
    }
}

// ---------- fp32 GEMM: C[nu x nI] = U[nu x 128] * I[nI x 128]^T ----------
__global__ __launch_bounds__(256) void gemm_kernel(const float* __restrict__ U,
                                                   const float* __restrict__ I,
                                                   float* __restrict__ C,
                                                   int nu, int nI) {
    __shared__ float Us[64][128];
    __shared__ float Is[64][128];
    const int t  = threadIdx.x;
    const int u0 = blockIdx.y * 128;
    const int i0 = blockIdx.x * 128;
    const int tx = t & 15, ty = t >> 4;
    float acc[8][8] = {};
    for (int ks = 0; ks < 2; ++ks) {
        if (ks) __syncthreads();
        #pragma unroll
        for (int it = 0; it < 8; ++it) {
            int f  = it * 256 + t;
            int r  = f >> 4;
            int k4 = (f & 15) << 2;
            int ug = u0 + r; if (ug >= nu) ug = nu - 1;
            f4 v = *(const f4*)(U + (size_t)ug * EMBED + ks * 64 + k4);
            int ig = i0 + r;
            f4 w = {0.f, 0.f, 0.f, 0.f};
            if (ig < nI) w = *(const f4*)(I + (size_t)ig * EMBED + ks * 64 + k4);
            int cs = r ^ (k4 & 28);
            Us[k4+0][cs] = v.x; Us[k4+1][cs] = v.y;
            Us[k4+2][cs] = v.z; Us[k4+3][cs] = v.w;
            Is[k4+0][cs] = w.x; Is[k4+1][cs] = w.y;
            Is[k4+2][cs] = w.z; Is[k4+3][cs] = w.w;
        }
        __syncthreads();
        #pragma unroll 4
        for (int k = 0; k < 64; ++k) {
            int sw = k & 28;
            f4 a0 = *(const f4*)&Us[k][(ty * 4) ^ sw];
            f4 a1 = *(const f4*)&Us[k][64 + ((ty * 4) ^ sw)];
            f4 b0 = *(const f4*)&Is[k][(tx * 4) ^ sw];
            f4 b1 = *(const f4*)&Is[k][64 + ((tx * 4) ^ sw)];
            float av[8] = {a0.x, a0.y, a0.z, a0.w, a1.x, a1.y, a1.z, a1.w};
            float bv[8] = {b0.x, b0.y, b0.z, b0.w, b1.x, b1.y, b1.z, b1.w};
            #pragma unroll
            for (int r2 = 0; r2 < 8; ++r2)
                #pragma unroll
                for (int c2 = 0; c2 < 8; ++c2)
                    acc[r2][c2] = fmaf(av[r2], bv[c2], acc[r2][c2]);
        }
    }
    bool full = (i0 + 128 <= nI);
    #pragma unroll
    for (int r2 = 0; r2 < 8; ++r2) {
        int row = u0 + (r2 >> 2) * 64 + ty * 4 + (r2 & 3);
        if (row >= nu) continue;
        float* Cr = C + (size_t)row * nI;
        #pragma unroll
        for (int mi = 0; mi < 2; ++mi) {
            int col = i0 + mi * 64 + tx * 4;
            if (full) {
                f4 o = {acc[r2][mi*4+0], acc[r2][mi*4+1],
                        acc[r2][mi*4+2], acc[r2][mi*4+3]};
                *(f4*)(Cr + col) = o;
            } else {
                #pragma unroll
                for (int c = 0; c < 4; ++c)
                    if (col + c < nI) Cr[col + c] = acc[r2][mi*4+c];
            }
        }
    }
}

extern "C" void kernel_launch(void* const* d_in, const int* in_sizes, int n_in,
                              void* d_out, int out_size, void* d_ws, size_t ws_size,
                              hipStream_t stream) {
    const float* emb   = (const float*)d_in[0];
    const float* ew    = (const float*)d_in[1];
    const int*   esrc  = (const int*)d_in[2];
    const int*   edst  = (const int*)d_in[3];
    const int*   users = (const int*)d_in[4];
    const int n_edges = in_sizes[1];
    const int n_nodes = in_sizes[0] / EMBED;
    const int nu      = in_sizes[4];

    // ---- workspace layout (~27.5 MB) ----
    char* ws = (char*)d_ws;
    int*   off_end = (int*)ws;                         // 400128 B
    int*   blkhist = (int*)(ws + 400128);              // 256*391*4 -> 400512 B
    int*   cursors = (int*)(ws + 800640);              // 400512 B
    int*   total   = (int*)(ws + 1201152);             // 391*4
    int*   bbase   = (int*)(ws + 1202816);             // (NB+1)*4
    float* ur      = (float*)(ws + 1204480);           // 512 KB
    float* ir      = (float*)(ws + 1204480 + 524288);  // 25.6 MB

    // ---- d_out doubles as scratch until the final GEMM overwrites it ----
    float*  out     = (float*)d_out;
    float*  acc     = out;                                        // 12.8M f
    __half* rep_a_h = (__half*)(out + (size_t)12800000);          // 25.6 MB
    __half* rep_b_h = (__half*)(out + (size_t)19200000);          // 25.6 MB
    __half* emb_h   = (__half*)(out + (size_t)25600000);          // 25.6 MB
    int2*   part_ep = (int2*)  (out + (size_t)32000000);          // 25.6 MB
    int2*   ep      = (int2*)  (out + (size_t)38400000);          // 25.6 MB

    const int epb = (n_edges + NBLK - 1) / NBLK;

    // 1) two-level CSR build
    part_hist   <<<NBLK, 256, 0, stream>>>(edst, blkhist, n_edges, epb);
    part_cursors<<<NB,   256, 0, stream>>>(blkhist, cursors, total);
    bucket_base_scan<<<1, 64, 0, stream>>>(total, bbase);
    part_scatter<<<NBLK, 256, 0, stream>>>(esrc, edst, ew, cursors, bbase,
                                           part_ep, n_edges, epb);
    bucket_csr  <<<NB,   512, 0, stream>>>(part_ep, bbase, off_end, ep, n_nodes);

    // 2) fp16 copy of embedding for layer-1 gathers
    int n4 = n_nodes * EMBED / 4;
    f2h_kernel<<<(n4 + 255) / 256, 256, 0, stream>>>(emb, emb_h, n4);

    // 3) three propagation layers (fp16 gather, fp32 acc); layer 1 fuses acc=emb+rep
    const int lgrid = (n_nodes + 3) / 4;
    layer_kernel<<<lgrid, 256, 0, stream>>>(emb_h,   rep_a_h, emb, acc, off_end, ep, n_nodes);
    layer_kernel<<<lgrid, 256, 0, stream>>>(rep_a_h, rep_b_h, acc, acc, off_end, ep, n_nodes);
    layer_kernel<<<lgrid, 256, 0, stream>>>(rep_b_h, rep_a_h, acc, acc, off_end, ep, n_nodes);

    // 4) gather user rows and item rows (x0.25 each -> product x1/16)
    gather_users<<<(nu * 32 + 255) / 256, 256, 0, stream>>>(users, acc, ur, nu);
    copy_items<<<(N_ITEMS * 32 + 255) / 256, 256, 0, stream>>>(acc, ir, N_ITEMS);

    // 5) scores = ur @ ir^T
    dim3 ggrid((N_ITEMS + 127) / 128, (nu + 127) / 128);
    gemm_kernel<<<ggrid, 256, 0, stream>>>(ur, ir, out, nu, N_ITEMS);
}

// Round 6
// 595.613 us; speedup vs baseline: 2.6845x; 1.2000x over previous
//
#include <hip/hip_runtime.h>
#include <hip/hip_bf16.h>
#include <hip/hip_fp16.h>

typedef float f4 __attribute__((ext_vector_type(4)));
typedef unsigned int u32x2 __attribute__((ext_vector_type(2)));
typedef _Float16 h8 __attribute__((ext_vector_type(8)));

__device__ __forceinline__ __half2 bits2h2(unsigned u) {
    union { unsigned u; __half2 h; } c; c.u = u; return c.h;
}
__device__ __forceinline__ unsigned h22bits(__half2 h) {
    union { unsigned u; __half2 h; } c; c.h = h; return c.u;
}

#define N_NODES   100000
#define EMBED     128
#define N_USERS_T 50000
#define N_ITEMS   50000

#define BSH   8                 // bucket = dst >> 8
#define NB    391               // ceil(100000 / 256)
#define NBLK  256               // partition blocks

// ---------- K1: per-block bucket histogram ----------
__global__ __launch_bounds__(256) void part_hist(const int* __restrict__ dst,
                                                 int* __restrict__ blkhist,
                                                 int n, int epb) {
    __shared__ int h[NB];
    for (int j = threadIdx.x; j < NB; j += 256) h[j] = 0;
    __syncthreads();
    int b = blockIdx.x, s = b * epb, e = min(n, s + epb);
    for (int i = s + (int)threadIdx.x; i < e; i += 256)
        atomicAdd(&h[dst[i] >> BSH], 1);
    __syncthreads();
    for (int j = threadIdx.x; j < NB; j += 256) blkhist[b * NB + j] = h[j];
}

// ---------- K2a: per-bucket exclusive scan across blocks ----------
__global__ __launch_bounds__(256) void part_cursors(const int* __restrict__ blkhist,
                                                    int* __restrict__ cursors,
                                                    int* __restrict__ total) {
    int bu = blockIdx.x, t = threadIdx.x;
    int v = blkhist[t * NB + bu];
    int lane = t & 63, wid = t >> 6;
    int x = v;
    #pragma unroll
    for (int off = 1; off < 64; off <<= 1) {
        int y = __shfl_up(x, off, 64);
        if (lane >= off) x += y;
    }
    __shared__ int ws4[4];
    if (lane == 63) ws4[wid] = x;
    __syncthreads();
    int add = 0;
    for (int j = 0; j < wid; ++j) add += ws4[j];
    cursors[t * NB + bu] = add + x - v;      // exclusive over blocks
    if (t == 255) total[bu] = add + x;       // bucket size
}

// ---------- K2b: bucket base (serial tiny scan) ----------
__global__ void bucket_base_scan(const int* __restrict__ total,
                                 int* __restrict__ base) {
    if (threadIdx.x == 0) {
        int s = 0;
        for (int j = 0; j < NB; ++j) { base[j] = s; s += total[j]; }
        base[NB] = s;
    }
}

// ---------- K3: partition into buckets (block-private slices) ----------
// part entry: .x = src | (dst_low8 << 17), .y = w bits
__global__ __launch_bounds__(256) void part_scatter(const int* __restrict__ src,
                                                    const int* __restrict__ dst,
                                                    const float* __restrict__ w,
                                                    const int* __restrict__ cursors,
                                                    const int* __restrict__ base,
                                                    int2* __restrict__ part,
                                                    int n, int epb) {
    __shared__ int cur[NB];
    int b = blockIdx.x;
    for (int j = threadIdx.x; j < NB; j += 256)
        cur[j] = base[j] + cursors[b * NB + j];
    __syncthreads();
    int s = b * epb, e = min(n, s + epb);
    for (int i = s + (int)threadIdx.x; i < e; i += 256) {
        int d = dst[i];
        int bu = d >> BSH;
        int p = atomicAdd(&cur[bu], 1);
        int2 pe;
        pe.x = src[i] | ((d & 255) << 17);
        pe.y = __float_as_int(w[i]);
        part[p] = pe;
    }
}

// ---------- K4: per-bucket fine CSR (count, scan, scatter; L2-local) ------
__global__ __launch_bounds__(512) void bucket_csr(const int2* __restrict__ part,
                                                  const int* __restrict__ base,
                                                  int* __restrict__ off_end,
                                                  int2* __restrict__ ep,
                                                  int n_nodes) {
    __shared__ int cnt[256], cur2[256], ws4[4];
    int bu = blockIdx.x, t = threadIdx.x;
    int b0 = base[bu], b1 = base[bu + 1];
    if (t < 256) cnt[t] = 0;
    __syncthreads();
    for (int i = b0 + t; i < b1; i += 512)
        atomicAdd(&cnt[(part[i].x >> 17) & 255], 1);
    __syncthreads();
    int lane = t & 63, wid = t >> 6;
    int v = 0, x = 0;
    if (t < 256) {
        v = cnt[t]; x = v;
        #pragma unroll
        for (int off = 1; off < 64; off <<= 1) {
            int y = __shfl_up(x, off, 64);
            if (lane >= off) x += y;
        }
        if (lane == 63) ws4[wid] = x;
    }
    __syncthreads();
    if (t < 256) {
        int add = 0;
        for (int j = 0; j < wid; ++j) add += ws4[j];
        int incl = add + x;
        int node = (bu << BSH) + t;
        if (node < n_nodes) off_end[node] = b0 + incl;
        cur2[t] = b0 + incl - v;             // exclusive start
    }
    __syncthreads();
    for (int i = b0 + t; i < b1; i += 512) {
        int2 pe = part[i];
        int dloc = (pe.x >> 17) & 255;
        int p = atomicAdd(&cur2[dloc], 1);
        int2 o; o.x = pe.x & 0x1FFFF; o.y = pe.y;
        ep[p] = o;
    }
}

// ---------- fp32 -> fp16 row conversion ----------
__global__ __launch_bounds__(256) void f2h_kernel(const float* __restrict__ in,
                                                  __half* __restrict__ out, int n4) {
    int i = blockIdx.x * 256 + threadIdx.x;
    if (i < n4) {
        f4 v = ((const f4*)in)[i];
        u32x2 o;
        o.x = h22bits(__floats2half2_rn(v.x, v.y));
        o.y = h22bits(__floats2half2_rn(v.z, v.w));
        ((u32x2*)out)[i] = o;
    }
}

// ---------- propagation layer: fp16 gather, fp32 accumulate ----------
__global__ __launch_bounds__(256) void layer_kernel(
        const __half* __restrict__ rep_in, __half* __restrict__ rep_out,
        const float* __restrict__ acc_in, float* __restrict__ acc_out,
        const int* __restrict__ off_end, const int2* __restrict__ ep,
        int n_nodes) {
    int node = blockIdx.x * 4 + (threadIdx.x >> 6);
    if (node >= n_nodes) return;
    int lane = threadIdx.x & 63;
    int half = lane >> 5;
    int l32  = lane & 31;
    int beg = (node == 0) ? 0 : off_end[node - 1];
    int end = off_end[node];
    f4 s = {0.f, 0.f, 0.f, 0.f};
    const u32x2* rp = (const u32x2*)rep_in;
    for (int chunk = beg; chunk < end; chunk += 64) {
        int idx = chunk + lane;
        int sn_l = 0, wb_l = 0;
        if (idx < end) { int2 e = ep[idx]; sn_l = e.x; wb_l = e.y; }
        int m = end - chunk; if (m > 64) m = 64;
        #pragma unroll 4
        for (int j = 0; j < m; j += 2) {
            int jj = j + half;                 // jj==m edge holds {0,0}: harmless
            int   sn = __shfl(sn_l, jj);
            float wt = __int_as_float(__shfl(wb_l, jj));
            u32x2 rv = rp[(size_t)sn * 32 + l32];
            float2 f0 = __half22float2(bits2h2(rv.x));
            float2 f1 = __half22float2(bits2h2(rv.y));
            s.x = fmaf(wt, f0.x, s.x);
            s.y = fmaf(wt, f0.y, s.y);
            s.z = fmaf(wt, f1.x, s.z);
            s.w = fmaf(wt, f1.y, s.w);
        }
    }
    s.x += __shfl_xor(s.x, 32);
    s.y += __shfl_xor(s.y, 32);
    s.z += __shfl_xor(s.z, 32);
    s.w += __shfl_xor(s.w, 32);
    size_t p = (size_t)node * 32 + l32;
    if (half == 0) {
        u32x2 ov;
        ov.x = h22bits(__floats2half2_rn(s.x, s.y));
        ov.y = h22bits(__floats2half2_rn(s.z, s.w));
        __builtin_nontemporal_store(ov, (u32x2*)rep_out + p);
    } else {
        f4 a = ((const f4*)acc_in)[p];
        a.x += s.x; a.y += s.y; a.z += s.z; a.w += s.w;
        __builtin_nontemporal_store(a, (f4*)acc_out + p);
    }
}

// ---------- gather user rows (x0.25, fp32 -> fp16) ----------
__global__ __launch_bounds__(256) void gather_users(const int* __restrict__ users,
                                                    const float* __restrict__ acc,
                                                    _Float16* __restrict__ ur, int nu) {
    int idx = blockIdx.x * 256 + threadIdx.x;
    int u = idx >> 5;
    int k = (idx & 31) * 4;
    if (u < nu) {
        f4 v = *(const f4*)(acc + (size_t)users[u] * EMBED + k);
        u32x2 o;
        o.x = h22bits(__floats2half2_rn(v.x * 0.25f, v.y * 0.25f));
        o.y = h22bits(__floats2half2_rn(v.z * 0.25f, v.w * 0.25f));
        *(u32x2*)(ur + (size_t)u * EMBED + k) = o;
    }
}

// ---------- copy item rows (x0.25, fp32 -> fp16) ----------
__global__ __launch_bounds__(256) void copy_items(const float* __restrict__ acc,
                                                  _Float16* __restrict__ ir, int ni) {
    int idx = blockIdx.x * 256 + threadIdx.x;
    int i = idx >> 5;
    int k = (idx & 31) * 4;
    if (i < ni) {
        f4 v = *(const f4*)(acc + (size_t)(N_USERS_T + i) * EMBED + k);
        u32x2 o;
        o.x = h22bits(__floats2half2_rn(v.x * 0.25f, v.y * 0.25f));
        o.y = h22bits(__floats2half2_rn(v.z * 0.25f, v.w * 0.25f));
        *(u32x2*)(ir + (size_t)i * EMBED + k) = o;
    }
}

// ---------- MFMA fp16 GEMM: C[nu x nI] = U[nu x 128] * I[nI x 128]^T -------
// One wave per 64x64 output tile; 4 i-tiles per block. A/B fragments are
// contiguous 16B row-major loads (no LDS). K=128 fully unrolled, 64 MFMA/wave.
__global__ __launch_bounds__(256) void gemm_mfma(const _Float16* __restrict__ U,
                                                 const _Float16* __restrict__ I,
                                                 float* __restrict__ C,
                                                 int nu, int nI) {
    int wave = threadIdx.x >> 6;
    int lane = threadIdx.x & 63;
    int i0 = (blockIdx.x * 4 + wave) * 64;
    int u0 = blockIdx.y * 64;
    if (i0 >= nI) return;
    int l16 = lane & 15;
    int kg  = lane >> 4;                  // 0..3 k-group
    f4 acc[4][4] = {};
    bool inb[4];
    #pragma unroll
    for (int nt = 0; nt < 4; ++nt) inb[nt] = (i0 + nt * 16 + l16) < nI;
    #pragma unroll
    for (int kk = 0; kk < 4; ++kk) {
        const int ko = kk * 32 + kg * 8;
        h8 a[4], b[4];
        #pragma unroll
        for (int mt = 0; mt < 4; ++mt)
            a[mt] = *(const h8*)(U + (size_t)(u0 + mt * 16 + l16) * EMBED + ko);
        #pragma unroll
        for (int nt = 0; nt < 4; ++nt) {
            h8 z = {};
            b[nt] = inb[nt] ? *(const h8*)(I + (size_t)(i0 + nt * 16 + l16) * EMBED + ko) : z;
        }
        #pragma unroll
        for (int mt = 0; mt < 4; ++mt)
            #pragma unroll
            for (int nt = 0; nt < 4; ++nt)
                acc[mt][nt] = __builtin_amdgcn_mfma_f32_16x16x32_f16(a[mt], b[nt], acc[mt][nt], 0, 0, 0);
    }
    // D layout: col = lane&15, row = (lane>>4)*4 + r
    #pragma unroll
    for (int mt = 0; mt < 4; ++mt) {
        #pragma unroll
        for (int r = 0; r < 4; ++r) {
            int row = u0 + mt * 16 + kg * 4 + r;
            if (row >= nu) continue;
            float* Cr = C + (size_t)row * nI;
            #pragma unroll
            for (int nt = 0; nt < 4; ++nt) {
                int col = i0 + nt * 16 + l16;
                if (col < nI)
                    __builtin_nontemporal_store(acc[mt][nt][r], Cr + col);
            }
        }
    }
}

extern "C" void kernel_launch(void* const* d_in, const int* in_sizes, int n_in,
                              void* d_out, int out_size, void* d_ws, size_t ws_size,
                              hipStream_t stream) {
    const float* emb   = (const float*)d_in[0];
    const float* ew    = (const float*)d_in[1];
    const int*   esrc  = (const int*)d_in[2];
    const int*   edst  = (const int*)d_in[3];
    const int*   users = (const int*)d_in[4];
    const int n_edges = in_sizes[1];
    const int n_nodes = in_sizes[0] / EMBED;
    const int nu      = in_sizes[4];

    // ---- workspace layout ----
    char* ws = (char*)d_ws;
    int*      off_end = (int*)ws;                         // 400128 B
    int*      blkhist = (int*)(ws + 400128);              // 400512 B
    int*      cursors = (int*)(ws + 800640);              // 400512 B
    int*      total   = (int*)(ws + 1201152);             // 391*4
    int*      bbase   = (int*)(ws + 1202816);             // (NB+1)*4
    _Float16* ur      = (_Float16*)(ws + 1204480);        // 256 KB
    _Float16* ir      = (_Float16*)(ws + 1204480 + 262144); // 12.8 MB

    // ---- d_out doubles as scratch until the final GEMM overwrites it ----
    float*  out     = (float*)d_out;
    float*  acc     = out;                                        // 12.8M f
    __half* rep_a_h = (__half*)(out + (size_t)12800000);          // 25.6 MB
    __half* rep_b_h = (__half*)(out + (size_t)19200000);          // 25.6 MB
    __half* emb_h   = (__half*)(out + (size_t)25600000);          // 25.6 MB
    int2*   part_ep = (int2*)  (out + (size_t)32000000);          // 25.6 MB
    int2*   ep      = (int2*)  (out + (size_t)38400000);          // 25.6 MB

    const int epb = (n_edges + NBLK - 1) / NBLK;

    // 1) two-level CSR build
    part_hist   <<<NBLK, 256, 0, stream>>>(edst, blkhist, n_edges, epb);
    part_cursors<<<NB,   256, 0, stream>>>(blkhist, cursors, total);
    bucket_base_scan<<<1, 64, 0, stream>>>(total, bbase);
    part_scatter<<<NBLK, 256, 0, stream>>>(esrc, edst, ew, cursors, bbase,
                                           part_ep, n_edges, epb);
    bucket_csr  <<<NB,   512, 0, stream>>>(part_ep, bbase, off_end, ep, n_nodes);

    // 2) fp16 copy of embedding for layer-1 gathers
    int n4 = n_nodes * EMBED / 4;
    f2h_kernel<<<(n4 + 255) / 256, 256, 0, stream>>>(emb, emb_h, n4);

    // 3) three propagation layers (fp16 gather, fp32 acc); layer 1 fuses acc=emb+rep
    const int lgrid = (n_nodes + 3) / 4;
    layer_kernel<<<lgrid, 256, 0, stream>>>(emb_h,   rep_a_h, emb, acc, off_end, ep, n_nodes);
    layer_kernel<<<lgrid, 256, 0, stream>>>(rep_a_h, rep_b_h, acc, acc, off_end, ep, n_nodes);
    layer_kernel<<<lgrid, 256, 0, stream>>>(rep_b_h, rep_a_h, acc, acc, off_end, ep, n_nodes);

    // 4) gather user/item rows (x0.25 each -> product x1/16), fp32 -> fp16
    gather_users<<<(nu * 32 + 255) / 256, 256, 0, stream>>>(users, acc, ur, nu);
    copy_items<<<(N_ITEMS * 32 + 255) / 256, 256, 0, stream>>>(acc, ir, N_ITEMS);

    // 5) scores = ur @ ir^T via fp16 MFMA (fp32 accumulate)
    dim3 ggrid((N_ITEMS + 255) / 256, (nu + 63) / 64);
    gemm_mfma<<<ggrid, 256, 0, stream>>>(ur, ir, out, nu, N_ITEMS);
}

// Round 7
// 533.471 us; speedup vs baseline: 2.9972x; 1.1165x over previous
//
#include <hip/hip_runtime.h>
#include <hip/hip_bf16.h>
#include <hip/hip_fp16.h>

typedef float f4 __attribute__((ext_vector_type(4)));
typedef unsigned int u32x2 __attribute__((ext_vector_type(2)));
typedef _Float16 h8 __attribute__((ext_vector_type(8)));

__device__ __forceinline__ __half2 bits2h2(unsigned u) {
    union { unsigned u; __half2 h; } c; c.u = u; return c.h;
}
__device__ __forceinline__ unsigned h22bits(__half2 h) {
    union { unsigned u; __half2 h; } c; c.h = h; return c.u;
}

#define N_NODES   100000
#define EMBED     128
#define N_USERS_T 50000
#define N_ITEMS   50000

#define BSH   8                 // bucket = dst >> 8
#define NB    391               // ceil(100000 / 256)
#define NBLK  256               // partition blocks

// ---------- K1: per-block bucket histogram ----------
__global__ __launch_bounds__(256) void part_hist(const int* __restrict__ dst,
                                                 int* __restrict__ blkhist,
                                                 int n, int epb) {
    __shared__ int h[NB];
    for (int j = threadIdx.x; j < NB; j += 256) h[j] = 0;
    __syncthreads();
    int b = blockIdx.x, s = b * epb, e = min(n, s + epb);
    for (int i = s + (int)threadIdx.x; i < e; i += 256)
        atomicAdd(&h[dst[i] >> BSH], 1);
    __syncthreads();
    for (int j = threadIdx.x; j < NB; j += 256) blkhist[b * NB + j] = h[j];
}

// ---------- K2a: per-bucket exclusive scan across blocks ----------
__global__ __launch_bounds__(256) void part_cursors(const int* __restrict__ blkhist,
                                                    int* __restrict__ cursors,
                                                    int* __restrict__ total) {
    int bu = blockIdx.x, t = threadIdx.x;
    int v = blkhist[t * NB + bu];
    int lane = t & 63, wid = t >> 6;
    int x = v;
    #pragma unroll
    for (int off = 1; off < 64; off <<= 1) {
        int y = __shfl_up(x, off, 64);
        if (lane >= off) x += y;
    }
    __shared__ int ws4[4];
    if (lane == 63) ws4[wid] = x;
    __syncthreads();
    int add = 0;
    for (int j = 0; j < wid; ++j) add += ws4[j];
    cursors[t * NB + bu] = add + x - v;      // exclusive over blocks
    if (t == 255) total[bu] = add + x;       // bucket size
}

// ---------- K2b: bucket base (serial tiny scan) ----------
__global__ void bucket_base_scan(const int* __restrict__ total,
                                 int* __restrict__ base) {
    if (threadIdx.x == 0) {
        int s = 0;
        for (int j = 0; j < NB; ++j) { base[j] = s; s += total[j]; }
        base[NB] = s;
    }
}

// ---------- K3: partition into buckets (block-private slices) ----------
// part entry: .x = src | (dst_low8 << 17), .y = w bits
__global__ __launch_bounds__(256) void part_scatter(const int* __restrict__ src,
                                                    const int* __restrict__ dst,
                                                    const float* __restrict__ w,
                                                    const int* __restrict__ cursors,
                                                    const int* __restrict__ base,
                                                    int2* __restrict__ part,
                                                    int n, int epb) {
    __shared__ int cur[NB];
    int b = blockIdx.x;
    for (int j = threadIdx.x; j < NB; j += 256)
        cur[j] = base[j] + cursors[b * NB + j];
    __syncthreads();
    int s = b * epb, e = min(n, s + epb);
    for (int i = s + (int)threadIdx.x; i < e; i += 256) {
        int d = dst[i];
        int bu = d >> BSH;
        int p = atomicAdd(&cur[bu], 1);
        int2 pe;
        pe.x = src[i] | ((d & 255) << 17);
        pe.y = __float_as_int(w[i]);
        part[p] = pe;
    }
}

// ---------- K4: per-bucket fine CSR; emits compressed edge u32 -------------
// edge u32 = src (17b) | wq (15b fixed-point w*32768)
__global__ __launch_bounds__(512) void bucket_csr(const int2* __restrict__ part,
                                                  const int* __restrict__ base,
                                                  int* __restrict__ off_end,
                                                  unsigned* __restrict__ ep,
                                                  int n_nodes) {
    __shared__ int cnt[256], cur2[256], ws4[4];
    int bu = blockIdx.x, t = threadIdx.x;
    int b0 = base[bu], b1 = base[bu + 1];
    if (t < 256) cnt[t] = 0;
    __syncthreads();
    for (int i = b0 + t; i < b1; i += 512)
        atomicAdd(&cnt[(part[i].x >> 17) & 255], 1);
    __syncthreads();
    int lane = t & 63, wid = t >> 6;
    int v = 0, x = 0;
    if (t < 256) {
        v = cnt[t]; x = v;
        #pragma unroll
        for (int off = 1; off < 64; off <<= 1) {
            int y = __shfl_up(x, off, 64);
            if (lane >= off) x += y;
        }
        if (lane == 63) ws4[wid] = x;
    }
    __syncthreads();
    if (t < 256) {
        int add = 0;
        for (int j = 0; j < wid; ++j) add += ws4[j];
        int incl = add + x;
        int node = (bu << BSH) + t;
        if (node < n_nodes) off_end[node] = b0 + incl;
        cur2[t] = b0 + incl - v;             // exclusive start
    }
    __syncthreads();
    for (int i = b0 + t; i < b1; i += 512) {
        int2 pe = part[i];
        int dloc = (pe.x >> 17) & 255;
        int p = atomicAdd(&cur2[dloc], 1);
        float wf = __int_as_float(pe.y);
        int wq = (int)(wf * 32768.f + 0.5f);
        wq = min(max(wq, 0), 32767);
        ep[p] = (unsigned)(pe.x & 0x1FFFF) | ((unsigned)wq << 17);
    }
}

// ---------- fp32 -> fp16 row conversion ----------
__global__ __launch_bounds__(256) void f2h_kernel(const float* __restrict__ in,
                                                  __half* __restrict__ out, int n4) {
    int i = blockIdx.x * 256 + threadIdx.x;
    if (i < n4) {
        f4 v = ((const f4*)in)[i];
        u32x2 o;
        o.x = h22bits(__floats2half2_rn(v.x, v.y));
        o.y = h22bits(__floats2half2_rn(v.z, v.w));
        ((u32x2*)out)[i] = o;
    }
}

// ---------- propagation layer: fp16 gather -> fp16 rep (no acc stream) -----
__global__ __launch_bounds__(256) void layer_kernel(
        const __half* __restrict__ rep_in, __half* __restrict__ rep_out,
        const int* __restrict__ off_end, const unsigned* __restrict__ ep,
        int n_nodes) {
    int node = blockIdx.x * 4 + (threadIdx.x >> 6);
    if (node >= n_nodes) return;
    int lane = threadIdx.x & 63;
    int half = lane >> 5;
    int l32  = lane & 31;
    int beg = (node == 0) ? 0 : off_end[node - 1];
    int end = off_end[node];
    f4 s = {0.f, 0.f, 0.f, 0.f};
    const u32x2* rp = (const u32x2*)rep_in;
    for (int chunk = beg; chunk < end; chunk += 64) {
        int idx = chunk + lane;
        unsigned ev = (idx < end) ? ep[idx] : 0u;
        int m = end - chunk; if (m > 64) m = 64;
        #pragma unroll 8
        for (int j = 0; j < m; j += 2) {
            unsigned v = __shfl(ev, j + half);   // j+half==m edge: lane m holds 0 -> harmless
            int   sn = v & 0x1FFFF;
            float wt = (float)(v >> 17) * (1.f / 32768.f);
            u32x2 rv = rp[(size_t)sn * 32 + l32];
            float2 f0 = __half22float2(bits2h2(rv.x));
            float2 f1 = __half22float2(bits2h2(rv.y));
            s.x = fmaf(wt, f0.x, s.x);
            s.y = fmaf(wt, f0.y, s.y);
            s.z = fmaf(wt, f1.x, s.z);
            s.w = fmaf(wt, f1.y, s.w);
        }
    }
    s.x += __shfl_xor(s.x, 32);
    s.y += __shfl_xor(s.y, 32);
    s.z += __shfl_xor(s.z, 32);
    s.w += __shfl_xor(s.w, 32);
    if (half == 0) {
        u32x2 ov;
        ov.x = h22bits(__floats2half2_rn(s.x, s.y));
        ov.y = h22bits(__floats2half2_rn(s.z, s.w));
        __builtin_nontemporal_store(ov, (u32x2*)rep_out + (size_t)node * 32 + l32);
    }
}

// ---------- final user rows: 0.25*(emb + r1 + r2 + r3), fp16 out ----------
__global__ __launch_bounds__(256) void gather_users(const int* __restrict__ users,
                                                    const float* __restrict__ emb,
                                                    const __half* __restrict__ r1,
                                                    const __half* __restrict__ r2,
                                                    const __half* __restrict__ r3,
                                                    _Float16* __restrict__ ur, int nu) {
    int idx = blockIdx.x * 256 + threadIdx.x;
    int u = idx >> 5;
    int q = idx & 31;
    if (u >= nu) return;
    size_t row = (size_t)users[u];
    f4 e = *(const f4*)(emb + row * EMBED + q * 4);
    size_t p = row * 32 + q;
    u32x2 a = ((const u32x2*)r1)[p];
    u32x2 b = ((const u32x2*)r2)[p];
    u32x2 c = ((const u32x2*)r3)[p];
    float2 a0 = __half22float2(bits2h2(a.x)), a1 = __half22float2(bits2h2(a.y));
    float2 b0 = __half22float2(bits2h2(b.x)), b1 = __half22float2(bits2h2(b.y));
    float2 c0 = __half22float2(bits2h2(c.x)), c1 = __half22float2(bits2h2(c.y));
    float v0 = (e.x + a0.x + b0.x + c0.x) * 0.25f;
    float v1 = (e.y + a0.y + b0.y + c0.y) * 0.25f;
    float v2 = (e.z + a1.x + b1.x + c1.x) * 0.25f;
    float v3 = (e.w + a1.y + b1.y + c1.y) * 0.25f;
    u32x2 o;
    o.x = h22bits(__floats2half2_rn(v0, v1));
    o.y = h22bits(__floats2half2_rn(v2, v3));
    *(u32x2*)(ur + (size_t)u * EMBED + q * 4) = o;
}

// ---------- final item rows: 0.25*(emb + r1 + r2 + r3), fp16 out ----------
__global__ __launch_bounds__(256) void copy_items(const float* __restrict__ emb,
                                                  const __half* __restrict__ r1,
                                                  const __half* __restrict__ r2,
                                                  const __half* __restrict__ r3,
                                                  _Float16* __restrict__ ir, int ni) {
    int idx = blockIdx.x * 256 + threadIdx.x;
    int i = idx >> 5;
    int q = idx & 31;
    if (i >= ni) return;
    size_t row = (size_t)(N_USERS_T + i);
    f4 e = *(const f4*)(emb + row * EMBED + q * 4);
    size_t p = row * 32 + q;
    u32x2 a = ((const u32x2*)r1)[p];
    u32x2 b = ((const u32x2*)r2)[p];
    u32x2 c = ((const u32x2*)r3)[p];
    float2 a0 = __half22float2(bits2h2(a.x)), a1 = __half22float2(bits2h2(a.y));
    float2 b0 = __half22float2(bits2h2(b.x)), b1 = __half22float2(bits2h2(b.y));
    float2 c0 = __half22float2(bits2h2(c.x)), c1 = __half22float2(bits2h2(c.y));
    float v0 = (e.x + a0.x + b0.x + c0.x) * 0.25f;
    float v1 = (e.y + a0.y + b0.y + c0.y) * 0.25f;
    float v2 = (e.z + a1.x + b1.x + c1.x) * 0.25f;
    float v3 = (e.w + a1.y + b1.y + c1.y) * 0.25f;
    u32x2 o;
    o.x = h22bits(__floats2half2_rn(v0, v1));
    o.y = h22bits(__floats2half2_rn(v2, v3));
    *(u32x2*)(ir + (size_t)i * EMBED + q * 4) = o;
}

// ---------- MFMA fp16 GEMM: C[nu x nI] = U[nu x 128] * I[nI x 128]^T -------
__global__ __launch_bounds__(256) void gemm_mfma(const _Float16* __restrict__ U,
                                                 const _Float16* __restrict__ I,
                                                 float* __restrict__ C,
                                                 int nu, int nI) {
    int wave = threadIdx.x >> 6;
    int lane = threadIdx.x & 63;
    int i0 = (blockIdx.x * 4 + wave) * 64;
    int u0 = blockIdx.y * 64;
    if (i0 >= nI) return;
    int l16 = lane & 15;
    int kg  = lane >> 4;
    f4 acc[4][4] = {};
    bool inb[4];
    #pragma unroll
    for (int nt = 0; nt < 4; ++nt) inb[nt] = (i0 + nt * 16 + l16) < nI;
    #pragma unroll
    for (int kk = 0; kk < 4; ++kk) {
        const int ko = kk * 32 + kg * 8;
        h8 a[4], b[4];
        #pragma unroll
        for (int mt = 0; mt < 4; ++mt)
            a[mt] = *(const h8*)(U + (size_t)(u0 + mt * 16 + l16) * EMBED + ko);
        #pragma unroll
        for (int nt = 0; nt < 4; ++nt) {
            h8 z = {};
            b[nt] = inb[nt] ? *(const h8*)(I + (size_t)(i0 + nt * 16 + l16) * EMBED + ko) : z;
        }
        #pragma unroll
        for (int mt = 0; mt < 4; ++mt)
            #pragma unroll
            for (int nt = 0; nt < 4; ++nt)
                acc[mt][nt] = __builtin_amdgcn_mfma_f32_16x16x32_f16(a[mt], b[nt], acc[mt][nt], 0, 0, 0);
    }
    #pragma unroll
    for (int mt = 0; mt < 4; ++mt) {
        #pragma unroll
        for (int r = 0; r < 4; ++r) {
            int row = u0 + mt * 16 + kg * 4 + r;
            if (row >= nu) continue;
            float* Cr = C + (size_t)row * nI;
            #pragma unroll
            for (int nt = 0; nt < 4; ++nt) {
                int col = i0 + nt * 16 + l16;
                if (col < nI)
                    __builtin_nontemporal_store(acc[mt][nt][r], Cr + col);
            }
        }
    }
}

extern "C" void kernel_launch(void* const* d_in, const int* in_sizes, int n_in,
                              void* d_out, int out_size, void* d_ws, size_t ws_size,
                              hipStream_t stream) {
    const float* emb   = (const float*)d_in[0];
    const float* ew    = (const float*)d_in[1];
    const int*   esrc  = (const int*)d_in[2];
    const int*   edst  = (const int*)d_in[3];
    const int*   users = (const int*)d_in[4];
    const int n_edges = in_sizes[1];
    const int n_nodes = in_sizes[0] / EMBED;
    const int nu      = in_sizes[4];

    // ---- workspace layout (~27 MB) ----
    char* ws = (char*)d_ws;
    int*      off_end = (int*)ws;                           // 400128 B
    int*      blkhist = (int*)(ws + 400128);                // 400512 B
    int*      cursors = (int*)(ws + 800640);                // 400512 B
    int*      total   = (int*)(ws + 1201152);               // 1664 B
    int*      bbase   = (int*)(ws + 1202816);               // 1664 B
    unsigned* epc     = (unsigned*)(ws + 1204480);          // 12.8 MB
    _Float16* ur      = (_Float16*)(ws + 1204480 + 12800000);           // 256 KB
    _Float16* ir      = (_Float16*)(ws + 1204480 + 12800000 + 262144);  // 12.8 MB

    // ---- d_out doubles as scratch until the final GEMM overwrites it ----
    __half* emb_h   = (__half*)d_out;                       // 25.6 MB
    __half* rep1_h  = emb_h + (size_t)12800000;             // 25.6 MB
    __half* rep2_h  = emb_h + (size_t)2 * 12800000;         // 25.6 MB
    __half* rep3_h  = emb_h + (size_t)3 * 12800000;         // 25.6 MB
    int2*   part_ep = (int2*)(emb_h + (size_t)4 * 12800000);// 25.6 MB (byte 102.4M)
    float*  out     = (float*)d_out;

    const int epb = (n_edges + NBLK - 1) / NBLK;

    // 1) two-level CSR build (compressed edge payload)
    part_hist   <<<NBLK, 256, 0, stream>>>(edst, blkhist, n_edges, epb);
    part_cursors<<<NB,   256, 0, stream>>>(blkhist, cursors, total);
    bucket_base_scan<<<1, 64, 0, stream>>>(total, bbase);
    part_scatter<<<NBLK, 256, 0, stream>>>(esrc, edst, ew, cursors, bbase,
                                           part_ep, n_edges, epb);
    bucket_csr  <<<NB,   512, 0, stream>>>(part_ep, bbase, off_end, epc, n_nodes);

    // 2) fp16 copy of embedding for layer-1 gathers
    int n4 = n_nodes * EMBED / 4;
    f2h_kernel<<<(n4 + 255) / 256, 256, 0, stream>>>(emb, emb_h, n4);

    // 3) three propagation layers (fp16 gather, fp32 math, fp16 rep out)
    const int lgrid = (n_nodes + 3) / 4;
    layer_kernel<<<lgrid, 256, 0, stream>>>(emb_h,  rep1_h, off_end, epc, n_nodes);
    layer_kernel<<<lgrid, 256, 0, stream>>>(rep1_h, rep2_h, off_end, epc, n_nodes);
    layer_kernel<<<lgrid, 256, 0, stream>>>(rep2_h, rep3_h, off_end, epc, n_nodes);

    // 4) final rows: 0.25*(emb + r1 + r2 + r3) -> fp16 ur / ir
    gather_users<<<(nu * 32 + 255) / 256, 256, 0, stream>>>(users, emb, rep1_h, rep2_h, rep3_h, ur, nu);
    copy_items<<<(N_ITEMS * 32 + 255) / 256, 256, 0, stream>>>(emb, rep1_h, rep2_h, rep3_h, ir, N_ITEMS);

    // 5) scores = ur @ ir^T via fp16 MFMA (fp32 accumulate)
    dim3 ggrid((N_ITEMS + 255) / 256, (nu + 63) / 64);
    gemm_mfma<<<ggrid, 256, 0, stream>>>(ur, ir, out, nu, N_ITEMS);
}